// Round 8
// baseline (2785.531 us; speedup 1.0000x reference)
//
#include <hip/hip_runtime.h>

// ---------------------------------------------------------------------------
// TGCN2 forward, MI355X gfx950. All float tensors fp32; edge_index i32.
// Math: H0=0 => TGCN R-gate dead, Hn=(1-Z)*H~, concat([c,0])@L == c@L_top;
// A(xW)L == (Ax)(WL) -> folded TGCN gate weights; head dots fused.
// GRU: spatial pipeline, NBLK blocks/layer x (256/NBLK) channels, LDS-resident
// weight slices, agent-scope fragment rings, per-block flags + per-step block
// barrier (R5 protocol; R6 barrier-free REGRESSED — barrier bounds wave skew).
// R8: NBLK=8 (96KB dynamic LDS, fan-in halved) with verified fallback NBLK=16.
// TGCN branch overlapped on a second captured stream (R7, worked).
// ---------------------------------------------------------------------------

typedef unsigned short u16;
typedef unsigned long long u64;
typedef short s8v __attribute__((ext_vector_type(8)));
typedef float f4v __attribute__((ext_vector_type(4)));

#define NBATCH 64
#define NNODE  512
#define DCIN   128
#define DHID   256
#define NEDGE  8192
#define RING   8
#define SLOTU16 16384   // 32KB per ring slot: 4 Mt x 8 kc x 1KB fragments

__device__ __forceinline__ u16 f2b(float f) {
    union { float f; unsigned int i; } v; v.f = f;
    unsigned int x = v.i;
    return (u16)((x + 0x7FFFu + ((x >> 16) & 1u)) >> 16);   // RNE
}
__device__ __forceinline__ float sigm(float x)  { return 1.0f / (1.0f + __expf(-x)); }
__device__ __forceinline__ float tanh_(float x) { return 1.0f - 2.0f / (1.0f + __expf(2.0f * x)); }
__device__ __forceinline__ f4v mfma16(s8v a, s8v b, f4v c) {
    return __builtin_amdgcn_mfma_f32_16x16x32_bf16(a, b, c, 0, 0, 0);
}
__device__ __forceinline__ s8v ld_ring(const u64* p) {
    union { u64 d[2]; s8v v; } u;
    u.d[0] = __hip_atomic_load(p,     __ATOMIC_RELAXED, __HIP_MEMORY_SCOPE_AGENT);
    u.d[1] = __hip_atomic_load(p + 1, __ATOMIC_RELAXED, __HIP_MEMORY_SCOPE_AGENT);
    return u.v;
}
__device__ __forceinline__ void st_ring(u64* p, s8v v) {
    union { s8v v; u64 d[2]; } u; u.v = v;
    __hip_atomic_store(p,     u.d[0], __ATOMIC_RELAXED, __HIP_MEMORY_SCOPE_AGENT);
    __hip_atomic_store(p + 1, u.d[1], __ATOMIC_RELAXED, __HIP_MEMORY_SCOPE_AGENT);
}

// --------------------------- graph preprocessing ---------------------------
__global__ void init_kernel(float* deg, int* counts, int* flags) {
    int i = blockIdx.x * blockDim.x + threadIdx.x;
    if (i < NNODE) { deg[i] = 2.0f; counts[i] = 1; }
    if (i < 128) flags[i] = 0;
}

__global__ void edge_deg_kernel(const int* __restrict__ ei, const float* __restrict__ ew,
                                float* deg, int* counts) {
    int e = blockIdx.x * blockDim.x + threadIdx.x;
    if (e < NEDGE) {
        int t = ei[NEDGE + e];
        atomicAdd(&deg[t], ew[e]);
        atomicAdd(&counts[t], 1);
    }
}

__global__ void scan_kernel(const float* __restrict__ deg, const int* __restrict__ counts,
                            float* __restrict__ dinv, int* __restrict__ rowptr,
                            int* __restrict__ cursor, int* __restrict__ col,
                            float* __restrict__ val) {
    __shared__ int sc[NNODE];
    int i = threadIdx.x;
    float d = deg[i];
    float di = (d > 0.0f) ? (1.0f / sqrtf(d)) : 0.0f;
    dinv[i] = di;
    int cnt = counts[i];
    sc[i] = cnt;
    __syncthreads();
    for (int ofs = 1; ofs < NNODE; ofs <<= 1) {
        int add = (i >= ofs) ? sc[i - ofs] : 0;
        __syncthreads();
        sc[i] += add;
        __syncthreads();
    }
    int ex = sc[i] - cnt;
    rowptr[i] = ex;
    if (i == NNODE - 1) rowptr[NNODE] = sc[NNODE - 1];
    col[ex] = i;
    val[ex] = di * 2.0f * di;
    cursor[i] = ex + 1;
}

__global__ void fill_kernel(const int* __restrict__ ei, const float* __restrict__ ew,
                            const float* __restrict__ dinv, int* cursor,
                            int* __restrict__ col, float* __restrict__ val) {
    int e = blockIdx.x * blockDim.x + threadIdx.x;
    if (e < NEDGE) {
        int s = ei[e], t = ei[NEDGE + e];
        int p = atomicAdd(&cursor[t], 1);
        col[p] = s;
        val[p] = dinv[s] * ew[e] * dinv[t];
    }
}

// Wf[2j+g][k] = sum_m Wg[k][m]*Lg_top[m][j]; bfold[2j+g] = bg@Lg_top[:,j]+lgb[j]
__global__ void fold_kernel(const float* __restrict__ Wz, const float* __restrict__ lzW,
                            const float* __restrict__ bz, const float* __restrict__ lzb,
                            const float* __restrict__ Wh, const float* __restrict__ lhW,
                            const float* __restrict__ bh, const float* __restrict__ lhb,
                            u16* __restrict__ Wf, float* __restrict__ bfold) {
    int nidx = blockIdx.x;
    int g = nidx & 1, j = nidx >> 1;
    int k = threadIdx.x;
    const float* W = g ? Wh : Wz;
    const float* L = g ? lhW : lzW;
    float acc = 0.0f;
    for (int m = 0; m < DHID; ++m)
        acc += W[k * DHID + m] * L[m * DHID + j];
    Wf[nidx * DCIN + k] = f2b(acc);
    if (k == 0) {
        const float* bg = g ? bh : bz;
        const float* lb = g ? lhb : lzb;
        float ab = 0.0f;
        for (int m = 0; m < DHID; ++m) ab += bg[m] * L[m * DHID + j];
        bfold[nidx] = ab + lb[j];
    }
}

// ----------------------------- weight repacks ------------------------------
// dst fragment-linear r-slices of 16 channels: flat = ((r*KC+kc)*3+g)*512+l*8
__global__ void repack_w_kernel(const float* __restrict__ Wih, const float* __restrict__ Whh,
                                int KCX, int KC, int KX, int KH, u16* __restrict__ dst) {
    int id = blockIdx.x * 256 + threadIdx.x;
    int total = 16 * KC * 3 * 64;
    if (id >= total) return;
    int l = id & 63; int rest = id >> 6;
    int g = rest % 3; rest /= 3;
    int kc = rest % KC; rest /= KC;
    int r = rest;
    int j = r * 16 + (l & 15);
    int q = l >> 4;
    const float* src; int k;
    if (kc < KCX) { src = Wih + (size_t)(g * 256 + j) * KX; k = kc * 32 + q * 8; }
    else          { src = Whh + (size_t)(g * 256 + j) * KH; k = (kc - KCX) * 32 + q * 8; }
    u16* d = dst + (((size_t)(r * KC + kc)) * 3 + g) * 512 + l * 8;
    #pragma unroll
    for (int e = 0; e < 8; ++e) d[e] = f2b(src[k + e]);
}

// xpack[t][Mt][kc][lane][8]: A-fragment-linear bf16 x
__global__ void repack_x_kernel(const float* __restrict__ x, u16* __restrict__ xpack) {
    int id = blockIdx.x * 256 + threadIdx.x;       // 524288
    int l = id & 63; int rest = id >> 6;
    int kc = rest & 3; rest >>= 2;
    int Mt = rest & 3; rest >>= 2;
    int t = rest;
    int b = Mt * 16 + (l & 15);
    int c = kc * 32 + (l >> 4) * 8;
    const float* s = x + ((size_t)b * NNODE + t) * DCIN + c;
    u16* d = xpack + (((size_t)t * 4 + Mt) * 4 + kc) * 512 + (size_t)l * 8;
    #pragma unroll
    for (int e = 0; e < 8; ++e) d[e] = f2b(s[e]);
}

// --------------- fused TGCN: aggregate + GEMM + cell + l1-dot --------------
__global__ __launch_bounds__(256)
void tgcn_kernel(const float* __restrict__ x, const int* __restrict__ rowptr,
                 const int* __restrict__ col, const float* __restrict__ val,
                 const u16* __restrict__ Wf, const float* __restrict__ bfold,
                 const float* __restrict__ l1W, float* __restrict__ hdot) {
    __shared__ u16 As[64][136];
    const int tid = threadIdx.x;
    const int bx = blockIdx.x;
    const int b = bx >> 3;
    const int n0 = (bx & 7) * 64;
    {
        const int c = tid & 127;
        const int half = tid >> 7;
        for (int it = 0; it < 32; ++it) {
            int r = it * 2 + half;
            int n = n0 + r;
            int s = rowptr[n], e = rowptr[n + 1];
            float acc = 0.0f;
            for (int i = s; i < e; ++i)
                acc += val[i] * x[((size_t)b * NNODE + col[i]) * DCIN + c];
            As[r][c] = f2b(acc);
        }
    }
    __syncthreads();
    const int w = tid >> 6, l = tid & 63;
    const int ncol = l & 15, q = l >> 4, ko = q * 8;
    s8v af[4];
    #pragma unroll
    for (int kc = 0; kc < 4; ++kc)
        af[kc] = *(const s8v*)(&As[w * 16 + ncol][kc * 32 + ko]);
    float partial[4] = {0.f, 0.f, 0.f, 0.f};
    for (int nc = 0; nc < 32; ++nc) {
        int n = nc * 16 + ncol;
        const u16* brow = Wf + (size_t)n * DCIN + ko;
        f4v acc = {0.f, 0.f, 0.f, 0.f};
        #pragma unroll
        for (int kc = 0; kc < 4; ++kc)
            acc = mfma16(af[kc], *(const s8v*)(brow + kc * 32), acc);
        float bias = bfold[n];
        float l1w = l1W[n >> 1];
        #pragma unroll
        for (int rr = 0; rr < 4; ++rr) {
            float v = acc[rr] + bias;
            float o = __shfl_xor(v, 1);
            float zpre = (ncol & 1) ? o : v;
            float hpre = (ncol & 1) ? v : o;
            float hn = (1.0f - sigm(zpre)) * tanh_(hpre);
            hn = hn > 0.0f ? hn : 0.0f;
            if (!(ncol & 1)) partial[rr] += hn * l1w;
        }
    }
    #pragma unroll
    for (int rr = 0; rr < 4; ++rr) {
        float p = partial[rr];
        p += __shfl_xor(p, 1); p += __shfl_xor(p, 2);
        p += __shfl_xor(p, 4); p += __shfl_xor(p, 8);
        if (ncol == 0)
            hdot[bx * 64 + w * 16 + q * 4 + rr] = p;
    }
}

// ------------- GRU: 2*NBLK-block spatial pipeline (R5 protocol) ------------
template <int NBLK>   // blocks per layer; CPB = 256/NBLK channels per block
__global__ __launch_bounds__(256)
void gru_pipe_kernel(const u16* __restrict__ xpack,
                     const u16* __restrict__ Wpk0, const u16* __restrict__ Wpk1,
                     const float* __restrict__ bih0, const float* __restrict__ bhh0,
                     const float* __restrict__ bih1, const float* __restrict__ bhh1,
                     const float* __restrict__ l2W,
                     u16* __restrict__ h0ring, u16* __restrict__ h1ring,
                     int* flags, float* __restrict__ gpartg) {
    constexpr int CPB = 256 / NBLK;
    constexpr int NCI = CPB / 16;               // n-tiles per block (1 or 2)
    extern __shared__ u16 wlds_dyn[];           // NCI*KC*3KB weight slice
    __shared__ u16 tile[4][16][CPB];            // per-wave epilogue staging

    const int tid = threadIdx.x;
    const int w = tid >> 6;                     // wave = M-tile (16 batches)
    const int l = tid & 63;
    const int q = l >> 4, ncol = l & 15;
    const bool isL1 = blockIdx.x >= NBLK;
    const int rblk = isL1 ? (blockIdx.x - NBLK) : blockIdx.x;
    const int KC = isL1 ? 16 : 12;

    int* fL0 = flags;
    int* fL1 = flags + 16;

    // ---- load weight slice (NCI consecutive 16-ch r-slices) into LDS ----
    {
        const s8v* src = (const s8v*)((isL1 ? Wpk1 : Wpk0)
                                      + (size_t)rblk * NCI * (KC * 3 * 512));
        s8v* dst = (s8v*)wlds_dyn;
        for (int i = tid; i < NCI * KC * 3 * 64; i += 256) dst[i] = src[i];
    }
    // ---- per-lane constants ----
    const float* bihp = isL1 ? bih1 : bih0;
    const float* bhhp = isL1 ? bhh1 : bhh0;
    float br[NCI], bz[NCI], bi[NCI], bhn[NCI], l2v[NCI];
    #pragma unroll
    for (int ci = 0; ci < NCI; ++ci) {
        int j = rblk * CPB + ci * 16 + ncol;
        br[ci]  = bihp[j] + bhhp[j];
        bz[ci]  = bihp[256 + j] + bhhp[256 + j];
        bi[ci]  = bihp[512 + j];
        bhn[ci] = bhhp[512 + j];
        l2v[ci] = isL1 ? l2W[j] : 0.0f;
    }
    float hreg[NCI][4];
    #pragma unroll
    for (int ci = 0; ci < NCI; ++ci)
        #pragma unroll
        for (int rr = 0; rr < 4; ++rr) hreg[ci][rr] = 0.0f;
    const int qbase = 2 * (rblk & 1);           // NCI==1 q-half publish only
    u16* myring = isL1 ? h1ring : h0ring;
    const s8v* wf = (const s8v*)wlds_dyn;
    __syncthreads();

    for (int t = 0; t < NNODE; ++t) {
        // ---- flag wait (monotone; every wave polls independently) ----
        {
            int tgt0 = isL1 ? t + 1 : t;
            int tgt1 = isL1 ? t : t - 7;
            while (true) {
                int v = 0x7fffffff, tg = -0x7fffffff;
                if (l < NBLK)                      { v = __hip_atomic_load(fL0 + l, __ATOMIC_RELAXED, __HIP_MEMORY_SCOPE_AGENT); tg = tgt0; }
                else if (l >= 16 && l < 16 + NBLK) { v = __hip_atomic_load(fL1 + (l - 16), __ATOMIC_RELAXED, __HIP_MEMORY_SCOPE_AGENT); tg = tgt1; }
                if (__all(v >= tg)) break;
                __builtin_amdgcn_s_sleep(2);
            }
            asm volatile("" ::: "memory");
        }
        // ---- A-fragment loads ----
        s8v a0[8], a1[8];
        if (isL1) {
            const u64* s0 = (const u64*)(h0ring + (size_t)(t & (RING - 1)) * SLOTU16);
            #pragma unroll
            for (int k = 0; k < 8; ++k) a0[k] = ld_ring(s0 + (size_t)(w * 8 + k) * 128 + l * 2);
            if (t > 0) {
                const u64* s1 = (const u64*)(h1ring + (size_t)((t - 1) & (RING - 1)) * SLOTU16);
                #pragma unroll
                for (int k = 0; k < 8; ++k) a1[k] = ld_ring(s1 + (size_t)(w * 8 + k) * 128 + l * 2);
            }
        } else {
            #pragma unroll
            for (int k = 0; k < 4; ++k)
                a0[k] = *(const s8v*)(xpack + (((size_t)t * 4 + w) * 4 + k) * 512 + (size_t)l * 8);
            if (t > 0) {
                const u64* s1 = (const u64*)(h0ring + (size_t)((t - 1) & (RING - 1)) * SLOTU16);
                #pragma unroll
                for (int k = 0; k < 8; ++k) a1[k] = ld_ring(s1 + (size_t)(w * 8 + k) * 128 + l * 2);
            }
        }
        // ---- MFMA (per n-tile; same per-output k order as R5) ----
        f4v accR[NCI], accZ[NCI], accNi[NCI], accNh[NCI];
        #pragma unroll
        for (int ci = 0; ci < NCI; ++ci) {
            accR[ci] = f4v{0,0,0,0}; accZ[ci] = f4v{0,0,0,0};
            accNi[ci] = f4v{0,0,0,0}; accNh[ci] = f4v{0,0,0,0};
        }
        if (isL1) {
            #pragma unroll
            for (int ci = 0; ci < NCI; ++ci) {
                const s8v* wfc = wf + ci * (16 * 3 * 64);
                #pragma unroll
                for (int kc = 0; kc < 8; ++kc) {
                    accR[ci]  = mfma16(a0[kc], wfc[(kc * 3 + 0) * 64 + l], accR[ci]);
                    accZ[ci]  = mfma16(a0[kc], wfc[(kc * 3 + 1) * 64 + l], accZ[ci]);
                    accNi[ci] = mfma16(a0[kc], wfc[(kc * 3 + 2) * 64 + l], accNi[ci]);
                }
                if (t > 0) {
                    #pragma unroll
                    for (int k = 0; k < 8; ++k) {
                        int kc = 8 + k;
                        accR[ci]  = mfma16(a1[k], wfc[(kc * 3 + 0) * 64 + l], accR[ci]);
                        accZ[ci]  = mfma16(a1[k], wfc[(kc * 3 + 1) * 64 + l], accZ[ci]);
                        accNh[ci] = mfma16(a1[k], wfc[(kc * 3 + 2) * 64 + l], accNh[ci]);
                    }
                }
            }
        } else {
            #pragma unroll
            for (int ci = 0; ci < NCI; ++ci) {
                const s8v* wfc = wf + ci * (12 * 3 * 64);
                #pragma unroll
                for (int kc = 0; kc < 4; ++kc) {
                    accR[ci]  = mfma16(a0[kc], wfc[(kc * 3 + 0) * 64 + l], accR[ci]);
                    accZ[ci]  = mfma16(a0[kc], wfc[(kc * 3 + 1) * 64 + l], accZ[ci]);
                    accNi[ci] = mfma16(a0[kc], wfc[(kc * 3 + 2) * 64 + l], accNi[ci]);
                }
                if (t > 0) {
                    #pragma unroll
                    for (int k = 0; k < 8; ++k) {
                        int kc = 4 + k;
                        accR[ci]  = mfma16(a1[k], wfc[(kc * 3 + 0) * 64 + l], accR[ci]);
                        accZ[ci]  = mfma16(a1[k], wfc[(kc * 3 + 1) * 64 + l], accZ[ci]);
                        accNh[ci] = mfma16(a1[k], wfc[(kc * 3 + 2) * 64 + l], accNh[ci]);
                    }
                }
            }
        }
        // ---- gate epilogue (fp32 h in registers) ----
        float pd[4] = {0.f, 0.f, 0.f, 0.f};
        #pragma unroll
        for (int ci = 0; ci < NCI; ++ci) {
            #pragma unroll
            for (int rr = 0; rr < 4; ++rr) {
                float rv = sigm(accR[ci][rr] + br[ci]);
                float zv = sigm(accZ[ci][rr] + bz[ci]);
                float nv = tanh_(accNi[ci][rr] + bi[ci] + rv * (accNh[ci][rr] + bhn[ci]));
                float hn = nv + zv * (hreg[ci][rr] - nv);
                hreg[ci][rr] = hn;
                tile[w][q * 4 + rr][ci * 16 + ncol] = f2b(hn);
                pd[rr] += hn * l2v[ci];
            }
        }
        if (isL1) {
            #pragma unroll
            for (int rr = 0; rr < 4; ++rr) {
                float v = pd[rr];
                v += __shfl_xor(v, 1); v += __shfl_xor(v, 2);
                v += __shfl_xor(v, 4); v += __shfl_xor(v, 8);
                if (ncol == 0)
                    gpartg[((size_t)t * NBLK + rblk) * 64 + w * 16 + q * 4 + rr] = v;
            }
        }
        // ---- publish slice fragment(s) (DS in-wave RAW order is safe) ----
        u64* slot = (u64*)(myring + (size_t)(t & (RING - 1)) * SLOTU16);
        if (NCI == 2) {
            // whole 1KB fragment kc=rblk, all 64 lanes
            s8v v = *(const s8v*)&tile[w][l & 15][(l >> 4) * 8];
            st_ring(slot + (size_t)(w * 8 + rblk) * 128 + l * 2, v);
        } else {
            if (q == qbase || q == qbase + 1) {
                s8v v = *(const s8v*)&tile[w][ncol][8 * (q - qbase)];
                st_ring(slot + (size_t)(w * 8 + (rblk >> 1)) * 128 + l * 2, v);
            }
        }
        __syncthreads();   // drains vmcnt (ring stores) + resets wave skew
        if (tid == 0)
            __hip_atomic_store((isL1 ? fL1 : fL0) + rblk, t + 1,
                               __ATOMIC_RELAXED, __HIP_MEMORY_SCOPE_AGENT);
    }
}

// ------------------------------- final head --------------------------------
__global__ __launch_bounds__(256)
void head_kernel(const float* __restrict__ gpartg, const float* __restrict__ hdot,
                 const float* __restrict__ l1b, const float* __restrict__ l2b,
                 const float* __restrict__ l3W, const float* __restrict__ l3b,
                 float* __restrict__ out, int nblk) {
    int idx = blockIdx.x * 256 + threadIdx.x;
    if (idx >= NBATCH * NNODE * 12) return;
    int r = idx / 12, oc = idx - r * 12;
    int b = r >> 9, n = r & 511;
    float g = 0.0f;
    for (int k = 0; k < nblk; ++k) g += gpartg[((size_t)n * nblk + k) * 64 + b];
    g += l2b[0];
    float hh = hdot[r] + l1b[0];
    out[idx] = g * l3W[oc] + hh * l3W[12 + oc] + l3b[oc];
}

// -------------------- static init (stream fork + LDS opt-in) ---------------
static hipStream_t g_side = nullptr;
static hipEvent_t  g_evA  = nullptr;
static hipEvent_t  g_evB  = nullptr;
static bool        g_dyn96_ok = false;
namespace {
struct SideInit {
    SideInit() {
        if (hipStreamCreateWithFlags(&g_side, hipStreamNonBlocking) != hipSuccess) g_side = nullptr;
        if (hipEventCreateWithFlags(&g_evA, hipEventDisableTiming) != hipSuccess) g_evA = nullptr;
        if (hipEventCreateWithFlags(&g_evB, hipEventDisableTiming) != hipSuccess) g_evB = nullptr;
        g_dyn96_ok = (hipFuncSetAttribute((const void*)&gru_pipe_kernel<8>,
                                          hipFuncAttributeMaxDynamicSharedMemorySize,
                                          96 * 1024) == hipSuccess);
    }
};
static SideInit g_side_init;
}

// ------------------------------ host launcher ------------------------------
extern "C" void kernel_launch(void* const* d_in, const int* in_sizes, int n_in,
                              void* d_out, int out_size, void* d_ws, size_t ws_size,
                              hipStream_t stream) {
    const float* x    = (const float*)d_in[0];
    const int*   ei   = (const int*)  d_in[1];
    const float* ew   = (const float*)d_in[2];
    const float* Wz   = (const float*)d_in[3];
    const float* bz   = (const float*)d_in[4];
    const float* lzW  = (const float*)d_in[5];
    const float* lzb  = (const float*)d_in[6];
    // d_in[7..10] (TGCN r-gate) unused: H0 == 0
    const float* Wh   = (const float*)d_in[11];
    const float* bh   = (const float*)d_in[12];
    const float* lhW  = (const float*)d_in[13];
    const float* lhb  = (const float*)d_in[14];
    const float* Wih0 = (const float*)d_in[15];
    const float* Whh0 = (const float*)d_in[16];
    const float* bih0 = (const float*)d_in[17];
    const float* bhh0 = (const float*)d_in[18];
    const float* Wih1 = (const float*)d_in[19];
    const float* Whh1 = (const float*)d_in[20];
    const float* bih1 = (const float*)d_in[21];
    const float* bhh1 = (const float*)d_in[22];
    const float* l1W  = (const float*)d_in[23];
    const float* l1b  = (const float*)d_in[24];
    const float* l2W  = (const float*)d_in[25];
    const float* l2b  = (const float*)d_in[26];
    const float* l3W  = (const float*)d_in[27];
    const float* l3b  = (const float*)d_in[28];

    char* ws = (char*)d_ws;
    size_t o = 0;
    auto take = [&](size_t nbytes) {
        char* p = ws + o;
        o = (o + nbytes + 255) & ~(size_t)255;
        return p;
    };
    float* deg    = (float*)take(NNODE * 4);
    float* dinv   = (float*)take(NNODE * 4);
    int*   rowptr = (int*)  take((NNODE + 1) * 4);
    int*   cursor = (int*)  take(NNODE * 4);
    int*   col    = (int*)  take((NEDGE + NNODE) * 4);
    float* val    = (float*)take((NEDGE + NNODE) * 4);
    u16*   Wf     = (u16*)  take((size_t)512 * DCIN * 2);
    float* bfold  = (float*)take(512 * 4);
    float* hdot   = (float*)take((size_t)NBATCH * NNODE * 4);
    float* gpartg = (float*)take((size_t)NNODE * 16 * 64 * 4);         // 2 MB
    u16*   xpack  = (u16*)  take((size_t)NNODE * 4 * 4 * 512 * 2);     // 8.4 MB
    u16*   Wpk0   = (u16*)  take((size_t)16 * 12 * 3 * 512 * 2);       // 590 KB
    u16*   Wpk1   = (u16*)  take((size_t)16 * 16 * 3 * 512 * 2);       // 786 KB
    u16*   h0ring = (u16*)  take((size_t)RING * SLOTU16 * 2);          // 256 KB
    u16*   h1ring = (u16*)  take((size_t)RING * SLOTU16 * 2);          // 256 KB
    int*   flags  = (int*)  take(512);
    if (o > ws_size) return;   // clean-failure signature: absmax == 4.57e-2

    const bool fork = (g_side && g_evA && g_evB);
    hipStream_t sideS = fork ? g_side : stream;

    // main: init (zeroes flags + deg/counts)
    init_kernel<<<2, 256, 0, stream>>>(deg, cursor, flags);

    if (fork) {
        hipEventRecord(g_evA, stream);
        hipStreamWaitEvent(sideS, g_evA, 0);
    }

    // side branch: graph preprocessing -> fold -> TGCN (independent of GRU)
    edge_deg_kernel<<<NEDGE / 256, 256, 0, sideS>>>(ei, ew, deg, cursor);
    scan_kernel<<<1, NNODE, 0, sideS>>>(deg, cursor, dinv, rowptr, cursor, col, val);
    fill_kernel<<<NEDGE / 256, 256, 0, sideS>>>(ei, ew, dinv, cursor, col, val);
    fold_kernel<<<512, DCIN, 0, sideS>>>(Wz, lzW, bz, lzb, Wh, lhW, bh, lhb, Wf, bfold);
    tgcn_kernel<<<512, 256, 0, sideS>>>(x, rowptr, col, val, Wf, bfold, l1W, hdot);
    if (fork) hipEventRecord(g_evB, sideS);

    // main branch: repacks -> GRU pipeline
    repack_w_kernel<<<(16 * 12 * 3 * 64 + 255) / 256, 256, 0, stream>>>(
        Wih0, Whh0, 4, 12, DCIN, DHID, Wpk0);
    repack_w_kernel<<<(16 * 16 * 3 * 64 + 255) / 256, 256, 0, stream>>>(
        Wih1, Whh1, 8, 16, DHID, DHID, Wpk1);
    repack_x_kernel<<<(NNODE * 4 * 4 * 64) / 256, 256, 0, stream>>>(x, xpack);

    int nblk;
    if (g_dyn96_ok) {
        nblk = 8;
        gru_pipe_kernel<8><<<16, 256, 96 * 1024, stream>>>(
            xpack, Wpk0, Wpk1, bih0, bhh0, bih1, bhh1, l2W,
            h0ring, h1ring, flags, gpartg);
    } else {
        nblk = 16;   // exact R5 configuration (48KB dynamic <= default limit)
        gru_pipe_kernel<16><<<32, 256, 48 * 1024, stream>>>(
            xpack, Wpk0, Wpk1, bih0, bhh0, bih1, bhh1, l2W,
            h0ring, h1ring, flags, gpartg);
    }

    // join + head
    if (fork) hipStreamWaitEvent(stream, g_evB, 0);
    head_kernel<<<(NBATCH * NNODE * 12 + 255) / 256, 256, 0, stream>>>(
        gpartg, hdot, l1b, l2b, l3W, l3b, (float*)d_out, nblk);
    (void)in_sizes; (void)n_in; (void)out_size;
}

// Round 9
// 2374.384 us; speedup vs baseline: 1.1732x; 1.1732x over previous
//
#include <hip/hip_runtime.h>

// ---------------------------------------------------------------------------
// TGCN2 forward, MI355X gfx950. All float tensors fp32; edge_index i32.
// Math: H0=0 => TGCN R-gate dead, Hn=(1-Z)*H~, concat([c,0])@L == c@L_top;
// A(xW)L == (Ax)(WL) -> folded TGCN gate weights; head dots fused.
// GRU: 32-block spatial pipeline (16 blocks/layer x 16 channels), LDS-resident
// weight slices, agent-scope fragment rings, per-block flags + per-step block
// barrier (R5 protocol). R9: phase-split MFMA ordering (work with satisfied
// deps runs BEFORE the critical wait) + L0 converts x fp32 in-kernel
// (repack_x removed; bit-identical values). R6's barrier-free variant
// REGRESSED (2557->3474us) — barrier kept. R8's 96KB dyn-LDS opt-in failed
// on this ROCm — no dynamic LDS. TGCN branch on a second captured stream (R7).
// ---------------------------------------------------------------------------

typedef unsigned short u16;
typedef unsigned long long u64;
typedef short s8v __attribute__((ext_vector_type(8)));
typedef float f4v __attribute__((ext_vector_type(4)));

#define NBATCH 64
#define NNODE  512
#define DCIN   128
#define DHID   256
#define NEDGE  8192
#define RING   8
#define SLOTU16 16384   // 32KB per ring slot: 4 Mt x 8 kc x 1KB fragments

__device__ __forceinline__ u16 f2b(float f) {
    union { float f; unsigned int i; } v; v.f = f;
    unsigned int x = v.i;
    return (u16)((x + 0x7FFFu + ((x >> 16) & 1u)) >> 16);   // RNE
}
__device__ __forceinline__ float sigm(float x)  { return 1.0f / (1.0f + __expf(-x)); }
__device__ __forceinline__ float tanh_(float x) { return 1.0f - 2.0f / (1.0f + __expf(2.0f * x)); }
__device__ __forceinline__ f4v mfma16(s8v a, s8v b, f4v c) {
    return __builtin_amdgcn_mfma_f32_16x16x32_bf16(a, b, c, 0, 0, 0);
}
__device__ __forceinline__ s8v ld_ring(const u64* p) {
    union { u64 d[2]; s8v v; } u;
    u.d[0] = __hip_atomic_load(p,     __ATOMIC_RELAXED, __HIP_MEMORY_SCOPE_AGENT);
    u.d[1] = __hip_atomic_load(p + 1, __ATOMIC_RELAXED, __HIP_MEMORY_SCOPE_AGENT);
    return u.v;
}
__device__ __forceinline__ void st_ring(u64* p, s8v v) {
    union { s8v v; u64 d[2]; } u; u.v = v;
    __hip_atomic_store(p,     u.d[0], __ATOMIC_RELAXED, __HIP_MEMORY_SCOPE_AGENT);
    __hip_atomic_store(p + 1, u.d[1], __ATOMIC_RELAXED, __HIP_MEMORY_SCOPE_AGENT);
}
// lanes 0..15 poll f[l]; lanes 16..31 poll g[l-16] (pass g=f,tgtg=INT_MIN to skip)
__device__ __forceinline__ void wait_joint(const int* f, int tgtf,
                                           const int* g, int tgtg, int l) {
    while (true) {
        int v = 0x7fffffff, tg = -0x7fffffff;
        if (l < 16)      { v = __hip_atomic_load(f + l, __ATOMIC_RELAXED, __HIP_MEMORY_SCOPE_AGENT); tg = tgtf; }
        else if (l < 32) { v = __hip_atomic_load(g + (l - 16), __ATOMIC_RELAXED, __HIP_MEMORY_SCOPE_AGENT); tg = tgtg; }
        if (__all(v >= tg)) break;
        __builtin_amdgcn_s_sleep(2);
    }
    asm volatile("" ::: "memory");
}
__device__ __forceinline__ void wait_one(const int* f, int tgt, int l) {
    while (true) {
        int v = 0x7fffffff;
        if (l < 16) v = __hip_atomic_load(f + l, __ATOMIC_RELAXED, __HIP_MEMORY_SCOPE_AGENT);
        if (__all(v >= tgt)) break;
        __builtin_amdgcn_s_sleep(2);
    }
    asm volatile("" ::: "memory");
}
// 8 consecutive fp32 -> bf16 fragment chunk (bit-identical to repack_x output)
__device__ __forceinline__ s8v cvt8(const float* p) {
    s8v r;
    #pragma unroll
    for (int e = 0; e < 8; ++e) r[e] = (short)f2b(p[e]);
    return r;
}

// --------------------------- graph preprocessing ---------------------------
__global__ void init_kernel(float* deg, int* counts, int* flags) {
    int i = blockIdx.x * blockDim.x + threadIdx.x;
    if (i < NNODE) { deg[i] = 2.0f; counts[i] = 1; }
    if (i < 128) flags[i] = 0;
}

__global__ void edge_deg_kernel(const int* __restrict__ ei, const float* __restrict__ ew,
                                float* deg, int* counts) {
    int e = blockIdx.x * blockDim.x + threadIdx.x;
    if (e < NEDGE) {
        int t = ei[NEDGE + e];
        atomicAdd(&deg[t], ew[e]);
        atomicAdd(&counts[t], 1);
    }
}

__global__ void scan_kernel(const float* __restrict__ deg, const int* __restrict__ counts,
                            float* __restrict__ dinv, int* __restrict__ rowptr,
                            int* __restrict__ cursor, int* __restrict__ col,
                            float* __restrict__ val) {
    __shared__ int sc[NNODE];
    int i = threadIdx.x;
    float d = deg[i];
    float di = (d > 0.0f) ? (1.0f / sqrtf(d)) : 0.0f;
    dinv[i] = di;
    int cnt = counts[i];
    sc[i] = cnt;
    __syncthreads();
    for (int ofs = 1; ofs < NNODE; ofs <<= 1) {
        int add = (i >= ofs) ? sc[i - ofs] : 0;
        __syncthreads();
        sc[i] += add;
        __syncthreads();
    }
    int ex = sc[i] - cnt;
    rowptr[i] = ex;
    if (i == NNODE - 1) rowptr[NNODE] = sc[NNODE - 1];
    col[ex] = i;
    val[ex] = di * 2.0f * di;
    cursor[i] = ex + 1;
}

__global__ void fill_kernel(const int* __restrict__ ei, const float* __restrict__ ew,
                            const float* __restrict__ dinv, int* cursor,
                            int* __restrict__ col, float* __restrict__ val) {
    int e = blockIdx.x * blockDim.x + threadIdx.x;
    if (e < NEDGE) {
        int s = ei[e], t = ei[NEDGE + e];
        int p = atomicAdd(&cursor[t], 1);
        col[p] = s;
        val[p] = dinv[s] * ew[e] * dinv[t];
    }
}

// Wf[2j+g][k] = sum_m Wg[k][m]*Lg_top[m][j]; bfold[2j+g] = bg@Lg_top[:,j]+lgb[j]
__global__ void fold_kernel(const float* __restrict__ Wz, const float* __restrict__ lzW,
                            const float* __restrict__ bz, const float* __restrict__ lzb,
                            const float* __restrict__ Wh, const float* __restrict__ lhW,
                            const float* __restrict__ bh, const float* __restrict__ lhb,
                            u16* __restrict__ Wf, float* __restrict__ bfold) {
    int nidx = blockIdx.x;
    int g = nidx & 1, j = nidx >> 1;
    int k = threadIdx.x;
    const float* W = g ? Wh : Wz;
    const float* L = g ? lhW : lzW;
    float acc = 0.0f;
    for (int m = 0; m < DHID; ++m)
        acc += W[k * DHID + m] * L[m * DHID + j];
    Wf[nidx * DCIN + k] = f2b(acc);
    if (k == 0) {
        const float* bg = g ? bh : bz;
        const float* lb = g ? lhb : lzb;
        float ab = 0.0f;
        for (int m = 0; m < DHID; ++m) ab += bg[m] * L[m * DHID + j];
        bfold[nidx] = ab + lb[j];
    }
}

// ----------------------------- weight repack -------------------------------
// dst fragment-linear: flat = ((r*KC + kc)*3 + g)*512 + l*8 ; r = 16-ch slice
__global__ void repack_w_kernel(const float* __restrict__ Wih, const float* __restrict__ Whh,
                                int KCX, int KC, int KX, int KH, u16* __restrict__ dst) {
    int id = blockIdx.x * 256 + threadIdx.x;
    int total = 16 * KC * 3 * 64;
    if (id >= total) return;
    int l = id & 63; int rest = id >> 6;
    int g = rest % 3; rest /= 3;
    int kc = rest % KC; rest /= KC;
    int r = rest;
    int j = r * 16 + (l & 15);
    int q = l >> 4;
    const float* src; int k;
    if (kc < KCX) { src = Wih + (size_t)(g * 256 + j) * KX; k = kc * 32 + q * 8; }
    else          { src = Whh + (size_t)(g * 256 + j) * KH; k = (kc - KCX) * 32 + q * 8; }
    u16* d = dst + (((size_t)(r * KC + kc)) * 3 + g) * 512 + l * 8;
    #pragma unroll
    for (int e = 0; e < 8; ++e) d[e] = f2b(src[k + e]);
}

// --------------- fused TGCN: aggregate + GEMM + cell + l1-dot --------------
__global__ __launch_bounds__(256)
void tgcn_kernel(const float* __restrict__ x, const int* __restrict__ rowptr,
                 const int* __restrict__ col, const float* __restrict__ val,
                 const u16* __restrict__ Wf, const float* __restrict__ bfold,
                 const float* __restrict__ l1W, float* __restrict__ hdot) {
    __shared__ u16 As[64][136];
    const int tid = threadIdx.x;
    const int bx = blockIdx.x;
    const int b = bx >> 3;
    const int n0 = (bx & 7) * 64;
    {
        const int c = tid & 127;
        const int half = tid >> 7;
        for (int it = 0; it < 32; ++it) {
            int r = it * 2 + half;
            int n = n0 + r;
            int s = rowptr[n], e = rowptr[n + 1];
            float acc = 0.0f;
            for (int i = s; i < e; ++i)
                acc += val[i] * x[((size_t)b * NNODE + col[i]) * DCIN + c];
            As[r][c] = f2b(acc);
        }
    }
    __syncthreads();
    const int w = tid >> 6, l = tid & 63;
    const int ncol = l & 15, q = l >> 4, ko = q * 8;
    s8v af[4];
    #pragma unroll
    for (int kc = 0; kc < 4; ++kc)
        af[kc] = *(const s8v*)(&As[w * 16 + ncol][kc * 32 + ko]);
    float partial[4] = {0.f, 0.f, 0.f, 0.f};
    for (int nc = 0; nc < 32; ++nc) {
        int n = nc * 16 + ncol;
        const u16* brow = Wf + (size_t)n * DCIN + ko;
        f4v acc = {0.f, 0.f, 0.f, 0.f};
        #pragma unroll
        for (int kc = 0; kc < 4; ++kc)
            acc = mfma16(af[kc], *(const s8v*)(brow + kc * 32), acc);
        float bias = bfold[n];
        float l1w = l1W[n >> 1];
        #pragma unroll
        for (int rr = 0; rr < 4; ++rr) {
            float v = acc[rr] + bias;
            float o = __shfl_xor(v, 1);
            float zpre = (ncol & 1) ? o : v;
            float hpre = (ncol & 1) ? v : o;
            float hn = (1.0f - sigm(zpre)) * tanh_(hpre);
            hn = hn > 0.0f ? hn : 0.0f;
            if (!(ncol & 1)) partial[rr] += hn * l1w;
        }
    }
    #pragma unroll
    for (int rr = 0; rr < 4; ++rr) {
        float p = partial[rr];
        p += __shfl_xor(p, 1); p += __shfl_xor(p, 2);
        p += __shfl_xor(p, 4); p += __shfl_xor(p, 8);
        if (ncol == 0)
            hdot[bx * 64 + w * 16 + q * 4 + rr] = p;
    }
}

// ---------- GRU: 32-block spatial pipeline, phase-split MFMA (R9) ----------
__global__ __launch_bounds__(256)
void gru_pipe_kernel(const float* __restrict__ x,
                     const u16* __restrict__ Wpk0, const u16* __restrict__ Wpk1,
                     const float* __restrict__ bih0, const float* __restrict__ bhh0,
                     const float* __restrict__ bih1, const float* __restrict__ bhh1,
                     const float* __restrict__ l2W,
                     u16* __restrict__ h0ring, u16* __restrict__ h1ring,
                     int* flags, float* __restrict__ gpartg) {
    __shared__ u16 wlds[16 * 3 * 512];          // 48KB max (L1); L0 uses 36KB
    __shared__ u16 tile[4][16][16];             // per-wave epilogue staging

    const int tid = threadIdx.x;
    const int w = tid >> 6;                     // wave = M-tile (16 batches)
    const int l = tid & 63;
    const int q = l >> 4, ncol = l & 15;
    const bool isL1 = blockIdx.x >= 16;
    const int rblk = blockIdx.x & 15;           // 16-channel output slice
    const int KC = isL1 ? 16 : 12;

    int* fL0 = flags;
    int* fL1 = flags + 16;

    // ---- load weight slice into LDS (once) ----
    {
        const s8v* src = (const s8v*)((isL1 ? Wpk1 : Wpk0) + (size_t)rblk * KC * 3 * 512);
        s8v* dst = (s8v*)wlds;
        for (int i = tid; i < KC * 3 * 64; i += 256) dst[i] = src[i];
    }
    // ---- per-lane constants ----
    const int j = rblk * 16 + ncol;
    const float* bihp = isL1 ? bih1 : bih0;
    const float* bhhp = isL1 ? bhh1 : bhh0;
    const float br = bihp[j] + bhhp[j];
    const float bz = bihp[256 + j] + bhhp[256 + j];
    const float bi = bihp[512 + j];
    const float bhn = bhhp[512 + j];
    const float l2v = isL1 ? l2W[j] : 0.0f;
    float hreg[4] = {0.f, 0.f, 0.f, 0.f};
    const int qbase = 2 * (rblk & 1);           // publish q-half for this slice
    u16* myring = isL1 ? h1ring : h0ring;
    const s8v* wf = (const s8v*)wlds;
    // L0's x A-fragment source: batch b = w*16+ncol, col base q*8
    const float* xrow = x + ((size_t)(w * 16 + ncol) * NNODE) * DCIN + q * 8;
    __syncthreads();

    for (int t = 0; t < NNODE; ++t) {
        f4v accR = {0,0,0,0}, accZ = {0,0,0,0}, accNi = {0,0,0,0}, accNh = {0,0,0,0};
        if (!isL1) {
            // ---- phase A: x-part — no dependency, runs before any wait ----
            const float* xp = xrow + (size_t)t * DCIN;
            #pragma unroll
            for (int kc = 0; kc < 4; ++kc) {
                s8v a = cvt8(xp + kc * 32);
                accR  = mfma16(a, wf[(kc * 3 + 0) * 64 + l], accR);
                accZ  = mfma16(a, wf[(kc * 3 + 1) * 64 + l], accZ);
                accNi = mfma16(a, wf[(kc * 3 + 2) * 64 + l], accNi);
            }
            // ---- phase B: wait h0(t-1) (+ ring slack), then h-part ----
            wait_joint(fL0, t, fL1, t - 7, l);
            if (t > 0) {
                const u64* s1 = (const u64*)(h0ring + (size_t)((t - 1) & (RING - 1)) * SLOTU16);
                s8v a1[8];
                #pragma unroll
                for (int k = 0; k < 8; ++k)
                    a1[k] = ld_ring(s1 + (size_t)(w * 8 + k) * 128 + l * 2);
                #pragma unroll
                for (int k = 0; k < 8; ++k) {
                    int kc = 4 + k;
                    accR  = mfma16(a1[k], wf[(kc * 3 + 0) * 64 + l], accR);
                    accZ  = mfma16(a1[k], wf[(kc * 3 + 1) * 64 + l], accZ);
                    accNh = mfma16(a1[k], wf[(kc * 3 + 2) * 64 + l], accNh);
                }
            }
        } else {
            // ---- phase A: own h1(t-1) — fL1>=t lands earlier than fL0>=t+1
            if (t > 0) {
                wait_one(fL1, t, l);
                const u64* s1 = (const u64*)(h1ring + (size_t)((t - 1) & (RING - 1)) * SLOTU16);
                s8v a1[8];
                #pragma unroll
                for (int k = 0; k < 8; ++k)
                    a1[k] = ld_ring(s1 + (size_t)(w * 8 + k) * 128 + l * 2);
                #pragma unroll
                for (int k = 0; k < 8; ++k) {
                    int kc = 8 + k;
                    accR  = mfma16(a1[k], wf[(kc * 3 + 0) * 64 + l], accR);
                    accZ  = mfma16(a1[k], wf[(kc * 3 + 1) * 64 + l], accZ);
                    accNh = mfma16(a1[k], wf[(kc * 3 + 2) * 64 + l], accNh);
                }
            }
            // ---- phase B: critical wait on h0(t) ----
            wait_one(fL0, t + 1, l);
            const u64* s0 = (const u64*)(h0ring + (size_t)(t & (RING - 1)) * SLOTU16);
            s8v a0[8];
            #pragma unroll
            for (int k = 0; k < 8; ++k)
                a0[k] = ld_ring(s0 + (size_t)(w * 8 + k) * 128 + l * 2);
            #pragma unroll
            for (int k = 0; k < 8; ++k) {
                accR  = mfma16(a0[k], wf[(k * 3 + 0) * 64 + l], accR);
                accZ  = mfma16(a0[k], wf[(k * 3 + 1) * 64 + l], accZ);
                accNi = mfma16(a0[k], wf[(k * 3 + 2) * 64 + l], accNi);
            }
        }
        // ---- gate epilogue (all gates in-wave; fp32 h in registers) ----
        float pd[4];
        #pragma unroll
        for (int rr = 0; rr < 4; ++rr) {
            float rv = sigm(accR[rr] + br);
            float zv = sigm(accZ[rr] + bz);
            float nv = tanh_(accNi[rr] + bi + rv * (accNh[rr] + bhn));
            float hn = nv + zv * (hreg[rr] - nv);
            hreg[rr] = hn;
            tile[w][q * 4 + rr][ncol] = f2b(hn);
            pd[rr] = hn * l2v;
        }
        if (isL1) {
            #pragma unroll
            for (int rr = 0; rr < 4; ++rr) {
                float v = pd[rr];
                v += __shfl_xor(v, 1); v += __shfl_xor(v, 2);
                v += __shfl_xor(v, 4); v += __shfl_xor(v, 8);
                if (ncol == 0)
                    gpartg[((size_t)t * 16 + rblk) * 64 + w * 16 + q * 4 + rr] = v;
            }
        }
        // ---- publish slice fragment (32 lanes whose q-half matches) ----
        if (q == qbase || q == qbase + 1) {
            s8v v = *(const s8v*)&tile[w][ncol][8 * (q - qbase)];
            u64* dst = (u64*)(myring + (size_t)(t & (RING - 1)) * SLOTU16)
                       + (size_t)(w * 8 + (rblk >> 1)) * 128 + l * 2;
            st_ring(dst, v);
        }
        __syncthreads();   // drains vmcnt (ring stores) + resets wave skew
        if (tid == 0)
            __hip_atomic_store((isL1 ? fL1 : fL0) + rblk, t + 1,
                               __ATOMIC_RELAXED, __HIP_MEMORY_SCOPE_AGENT);
    }
}

// ------------------------------- final head --------------------------------
__global__ __launch_bounds__(256)
void head_kernel(const float* __restrict__ gpartg, const float* __restrict__ hdot,
                 const float* __restrict__ l1b, const float* __restrict__ l2b,
                 const float* __restrict__ l3W, const float* __restrict__ l3b,
                 float* __restrict__ out) {
    int idx = blockIdx.x * 256 + threadIdx.x;
    if (idx >= NBATCH * NNODE * 12) return;
    int r = idx / 12, oc = idx - r * 12;
    int b = r >> 9, n = r & 511;
    float g = 0.0f;
    #pragma unroll
    for (int k = 0; k < 16; ++k) g += gpartg[((size_t)n * 16 + k) * 64 + b];
    g += l2b[0];
    float hh = hdot[r] + l1b[0];
    out[idx] = g * l3W[oc] + hh * l3W[12 + oc] + l3b[oc];
}

// ---------------------- static side stream (for capture fork) --------------
static hipStream_t g_side = nullptr;
static hipEvent_t  g_evA  = nullptr;
static hipEvent_t  g_evB  = nullptr;
namespace {
struct SideInit {
    SideInit() {
        if (hipStreamCreateWithFlags(&g_side, hipStreamNonBlocking) != hipSuccess) g_side = nullptr;
        if (hipEventCreateWithFlags(&g_evA, hipEventDisableTiming) != hipSuccess) g_evA = nullptr;
        if (hipEventCreateWithFlags(&g_evB, hipEventDisableTiming) != hipSuccess) g_evB = nullptr;
    }
};
static SideInit g_side_init;
}

// ------------------------------ host launcher ------------------------------
extern "C" void kernel_launch(void* const* d_in, const int* in_sizes, int n_in,
                              void* d_out, int out_size, void* d_ws, size_t ws_size,
                              hipStream_t stream) {
    const float* x    = (const float*)d_in[0];
    const int*   ei   = (const int*)  d_in[1];
    const float* ew   = (const float*)d_in[2];
    const float* Wz   = (const float*)d_in[3];
    const float* bz   = (const float*)d_in[4];
    const float* lzW  = (const float*)d_in[5];
    const float* lzb  = (const float*)d_in[6];
    // d_in[7..10] (TGCN r-gate) unused: H0 == 0
    const float* Wh   = (const float*)d_in[11];
    const float* bh   = (const float*)d_in[12];
    const float* lhW  = (const float*)d_in[13];
    const float* lhb  = (const float*)d_in[14];
    const float* Wih0 = (const float*)d_in[15];
    const float* Whh0 = (const float*)d_in[16];
    const float* bih0 = (const float*)d_in[17];
    const float* bhh0 = (const float*)d_in[18];
    const float* Wih1 = (const float*)d_in[19];
    const float* Whh1 = (const float*)d_in[20];
    const float* bih1 = (const float*)d_in[21];
    const float* bhh1 = (const float*)d_in[22];
    const float* l1W  = (const float*)d_in[23];
    const float* l1b  = (const float*)d_in[24];
    const float* l2W  = (const float*)d_in[25];
    const float* l2b  = (const float*)d_in[26];
    const float* l3W  = (const float*)d_in[27];
    const float* l3b  = (const float*)d_in[28];

    char* ws = (char*)d_ws;
    size_t o = 0;
    auto take = [&](size_t nbytes) {
        char* p = ws + o;
        o = (o + nbytes + 255) & ~(size_t)255;
        return p;
    };
    float* deg    = (float*)take(NNODE * 4);
    float* dinv   = (float*)take(NNODE * 4);
    int*   rowptr = (int*)  take((NNODE + 1) * 4);
    int*   cursor = (int*)  take(NNODE * 4);
    int*   col    = (int*)  take((NEDGE + NNODE) * 4);
    float* val    = (float*)take((NEDGE + NNODE) * 4);
    u16*   Wf     = (u16*)  take((size_t)512 * DCIN * 2);
    float* bfold  = (float*)take(512 * 4);
    float* hdot   = (float*)take((size_t)NBATCH * NNODE * 4);
    float* gpartg = (float*)take((size_t)NNODE * 16 * 64 * 4);         // 2 MB
    u16*   Wpk0   = (u16*)  take((size_t)16 * 12 * 3 * 512 * 2);       // 590 KB
    u16*   Wpk1   = (u16*)  take((size_t)16 * 16 * 3 * 512 * 2);       // 786 KB
    u16*   h0ring = (u16*)  take((size_t)RING * SLOTU16 * 2);          // 256 KB
    u16*   h1ring = (u16*)  take((size_t)RING * SLOTU16 * 2);          // 256 KB
    int*   flags  = (int*)  take(512);
    if (o > ws_size) return;   // clean-failure signature: absmax == 4.57e-2

    const bool fork = (g_side && g_evA && g_evB);
    hipStream_t sideS = fork ? g_side : stream;

    // main: init (zeroes flags + deg/counts)
    init_kernel<<<2, 256, 0, stream>>>(deg, cursor, flags);

    if (fork) {
        hipEventRecord(g_evA, stream);
        hipStreamWaitEvent(sideS, g_evA, 0);
    }

    // side branch: graph preprocessing -> fold -> TGCN (independent of GRU)
    edge_deg_kernel<<<NEDGE / 256, 256, 0, sideS>>>(ei, ew, deg, cursor);
    scan_kernel<<<1, NNODE, 0, sideS>>>(deg, cursor, dinv, rowptr, cursor, col, val);
    fill_kernel<<<NEDGE / 256, 256, 0, sideS>>>(ei, ew, dinv, cursor, col, val);
    fold_kernel<<<512, DCIN, 0, sideS>>>(Wz, lzW, bz, lzb, Wh, lhW, bh, lhb, Wf, bfold);
    tgcn_kernel<<<512, 256, 0, sideS>>>(x, rowptr, col, val, Wf, bfold, l1W, hdot);
    if (fork) hipEventRecord(g_evB, sideS);

    // main branch: weight repacks -> GRU pipeline (x converted in-kernel)
    repack_w_kernel<<<(16 * 12 * 3 * 64 + 255) / 256, 256, 0, stream>>>(
        Wih0, Whh0, 4, 12, DCIN, DHID, Wpk0);
    repack_w_kernel<<<(16 * 16 * 3 * 64 + 255) / 256, 256, 0, stream>>>(
        Wih1, Whh1, 8, 16, DHID, DHID, Wpk1);
    gru_pipe_kernel<<<32, 256, 0, stream>>>(x, Wpk0, Wpk1, bih0, bhh0,
                                            bih1, bhh1, l2W, h0ring, h1ring,
                                            flags, gpartg);

    // join + head
    if (fork) hipStreamWaitEvent(stream, g_evB, 0);
    head_kernel<<<(NBATCH * NNODE * 12 + 255) / 256, 256, 0, stream>>>(
        gpartg, hdot, l1b, l2b, l3W, l3b, (float*)d_out);
    (void)in_sizes; (void)n_in; (void)out_size;
}

// Round 10
// 2276.783 us; speedup vs baseline: 1.2235x; 1.0429x over previous
//
#include <hip/hip_runtime.h>

// ---------------------------------------------------------------------------
// TGCN2 forward, MI355X gfx950. All float tensors fp32; edge_index i32.
// Math: H0=0 => TGCN R-gate dead, Hn=(1-Z)*H~, concat([c,0])@L == c@L_top;
// A(xW)L == (Ax)(WL) -> folded TGCN gate weights; head dots fused.
// GRU: 32-block spatial pipeline (16 blocks/layer x 16 channels), LDS-resident
// weight slices, agent-scope fragment rings. R10: per-WAVE stamps co-located
// with ring slots (drain -> stamp store, no barrier/leader on the visibility
// path; per-step barrier KEPT after publish for skew reset — R6 showed
// removing it regresses), and L1 consumes h0 BEFORE its h1 self-loop wait.
// R9: phase-split (x-part pre-wait) + in-kernel x conversion. TGCN branch on
// a second captured stream (R7).
// ---------------------------------------------------------------------------

typedef unsigned short u16;
typedef unsigned long long u64;
typedef short s8v __attribute__((ext_vector_type(8)));
typedef float f4v __attribute__((ext_vector_type(4)));

#define NBATCH 64
#define NNODE  512
#define DCIN   128
#define DHID   256
#define NEDGE  8192
#define RING   8
#define SLOTU16 16384   // 32KB per ring slot: 4 Mt x 8 kc x 1KB fragments

__device__ __forceinline__ u16 f2b(float f) {
    union { float f; unsigned int i; } v; v.f = f;
    unsigned int x = v.i;
    return (u16)((x + 0x7FFFu + ((x >> 16) & 1u)) >> 16);   // RNE
}
__device__ __forceinline__ float sigm(float x)  { return 1.0f / (1.0f + __expf(-x)); }
__device__ __forceinline__ float tanh_(float x) { return 1.0f - 2.0f / (1.0f + __expf(2.0f * x)); }
__device__ __forceinline__ f4v mfma16(s8v a, s8v b, f4v c) {
    return __builtin_amdgcn_mfma_f32_16x16x32_bf16(a, b, c, 0, 0, 0);
}
__device__ __forceinline__ s8v ld_ring(const u64* p) {
    union { u64 d[2]; s8v v; } u;
    u.d[0] = __hip_atomic_load(p,     __ATOMIC_RELAXED, __HIP_MEMORY_SCOPE_AGENT);
    u.d[1] = __hip_atomic_load(p + 1, __ATOMIC_RELAXED, __HIP_MEMORY_SCOPE_AGENT);
    return u.v;
}
__device__ __forceinline__ void st_ring(u64* p, s8v v) {
    union { s8v v; u64 d[2]; } u; u.v = v;
    __hip_atomic_store(p,     u.d[0], __ATOMIC_RELAXED, __HIP_MEMORY_SCOPE_AGENT);
    __hip_atomic_store(p + 1, u.d[1], __ATOMIC_RELAXED, __HIP_MEMORY_SCOPE_AGENT);
}
// lanes 0..15 poll 16 per-wave stamps (one 64B line)
__device__ __forceinline__ void wait_stamp(const int* sp, int tgt, int l) {
    while (true) {
        int v = 0x7fffffff;
        if (l < 16) v = __hip_atomic_load(sp + l, __ATOMIC_RELAXED, __HIP_MEMORY_SCOPE_AGENT);
        if (__all(v >= tgt)) break;
        __builtin_amdgcn_s_sleep(2);
    }
    asm volatile("" ::: "memory");
}
// stamps on lanes 0..15, block-flag slack on lanes 16..31
__device__ __forceinline__ void wait_stamp_slack(const int* sp, int tgt,
                                                 const int* fp, int tgtf, int l) {
    while (true) {
        int v = 0x7fffffff, tg = -0x7fffffff;
        if (l < 16)      { v = __hip_atomic_load(sp + l, __ATOMIC_RELAXED, __HIP_MEMORY_SCOPE_AGENT); tg = tgt; }
        else if (l < 32) { v = __hip_atomic_load(fp + (l - 16), __ATOMIC_RELAXED, __HIP_MEMORY_SCOPE_AGENT); tg = tgtf; }
        if (__all(v >= tg)) break;
        __builtin_amdgcn_s_sleep(2);
    }
    asm volatile("" ::: "memory");
}
// 8 consecutive fp32 -> bf16 fragment chunk (bit-identical to repack path)
__device__ __forceinline__ s8v cvt8(const float* p) {
    s8v r;
    #pragma unroll
    for (int e = 0; e < 8; ++e) r[e] = (short)f2b(p[e]);
    return r;
}

// --------------------------- graph preprocessing ---------------------------
__global__ void init_kernel(float* deg, int* counts, int* syncb) {
    int i = blockIdx.x * blockDim.x + threadIdx.x;
    if (i < NNODE) { deg[i] = 2.0f; counts[i] = 1; }
    if (i < 2048) syncb[i] = 0;   // flags + per-wave stamps
}

__global__ void edge_deg_kernel(const int* __restrict__ ei, const float* __restrict__ ew,
                                float* deg, int* counts) {
    int e = blockIdx.x * blockDim.x + threadIdx.x;
    if (e < NEDGE) {
        int t = ei[NEDGE + e];
        atomicAdd(&deg[t], ew[e]);
        atomicAdd(&counts[t], 1);
    }
}

__global__ void scan_kernel(const float* __restrict__ deg, const int* __restrict__ counts,
                            float* __restrict__ dinv, int* __restrict__ rowptr,
                            int* __restrict__ cursor, int* __restrict__ col,
                            float* __restrict__ val) {
    __shared__ int sc[NNODE];
    int i = threadIdx.x;
    float d = deg[i];
    float di = (d > 0.0f) ? (1.0f / sqrtf(d)) : 0.0f;
    dinv[i] = di;
    int cnt = counts[i];
    sc[i] = cnt;
    __syncthreads();
    for (int ofs = 1; ofs < NNODE; ofs <<= 1) {
        int add = (i >= ofs) ? sc[i - ofs] : 0;
        __syncthreads();
        sc[i] += add;
        __syncthreads();
    }
    int ex = sc[i] - cnt;
    rowptr[i] = ex;
    if (i == NNODE - 1) rowptr[NNODE] = sc[NNODE - 1];
    col[ex] = i;
    val[ex] = di * 2.0f * di;
    cursor[i] = ex + 1;
}

__global__ void fill_kernel(const int* __restrict__ ei, const float* __restrict__ ew,
                            const float* __restrict__ dinv, int* cursor,
                            int* __restrict__ col, float* __restrict__ val) {
    int e = blockIdx.x * blockDim.x + threadIdx.x;
    if (e < NEDGE) {
        int s = ei[e], t = ei[NEDGE + e];
        int p = atomicAdd(&cursor[t], 1);
        col[p] = s;
        val[p] = dinv[s] * ew[e] * dinv[t];
    }
}

// Wf[2j+g][k] = sum_m Wg[k][m]*Lg_top[m][j]; bfold[2j+g] = bg@Lg_top[:,j]+lgb[j]
__global__ void fold_kernel(const float* __restrict__ Wz, const float* __restrict__ lzW,
                            const float* __restrict__ bz, const float* __restrict__ lzb,
                            const float* __restrict__ Wh, const float* __restrict__ lhW,
                            const float* __restrict__ bh, const float* __restrict__ lhb,
                            u16* __restrict__ Wf, float* __restrict__ bfold) {
    int nidx = blockIdx.x;
    int g = nidx & 1, j = nidx >> 1;
    int k = threadIdx.x;
    const float* W = g ? Wh : Wz;
    const float* L = g ? lhW : lzW;
    float acc = 0.0f;
    for (int m = 0; m < DHID; ++m)
        acc += W[k * DHID + m] * L[m * DHID + j];
    Wf[nidx * DCIN + k] = f2b(acc);
    if (k == 0) {
        const float* bg = g ? bh : bz;
        const float* lb = g ? lhb : lzb;
        float ab = 0.0f;
        for (int m = 0; m < DHID; ++m) ab += bg[m] * L[m * DHID + j];
        bfold[nidx] = ab + lb[j];
    }
}

// ----------------------------- weight repack -------------------------------
__global__ void repack_w_kernel(const float* __restrict__ Wih, const float* __restrict__ Whh,
                                int KCX, int KC, int KX, int KH, u16* __restrict__ dst) {
    int id = blockIdx.x * 256 + threadIdx.x;
    int total = 16 * KC * 3 * 64;
    if (id >= total) return;
    int l = id & 63; int rest = id >> 6;
    int g = rest % 3; rest /= 3;
    int kc = rest % KC; rest /= KC;
    int r = rest;
    int j = r * 16 + (l & 15);
    int q = l >> 4;
    const float* src; int k;
    if (kc < KCX) { src = Wih + (size_t)(g * 256 + j) * KX; k = kc * 32 + q * 8; }
    else          { src = Whh + (size_t)(g * 256 + j) * KH; k = (kc - KCX) * 32 + q * 8; }
    u16* d = dst + (((size_t)(r * KC + kc)) * 3 + g) * 512 + l * 8;
    #pragma unroll
    for (int e = 0; e < 8; ++e) d[e] = f2b(src[k + e]);
}

// --------------- fused TGCN: aggregate + GEMM + cell + l1-dot --------------
__global__ __launch_bounds__(256)
void tgcn_kernel(const float* __restrict__ x, const int* __restrict__ rowptr,
                 const int* __restrict__ col, const float* __restrict__ val,
                 const u16* __restrict__ Wf, const float* __restrict__ bfold,
                 const float* __restrict__ l1W, float* __restrict__ hdot) {
    __shared__ u16 As[64][136];
    const int tid = threadIdx.x;
    const int bx = blockIdx.x;
    const int b = bx >> 3;
    const int n0 = (bx & 7) * 64;
    {
        const int c = tid & 127;
        const int half = tid >> 7;
        for (int it = 0; it < 32; ++it) {
            int r = it * 2 + half;
            int n = n0 + r;
            int s = rowptr[n], e = rowptr[n + 1];
            float acc = 0.0f;
            for (int i = s; i < e; ++i)
                acc += val[i] * x[((size_t)b * NNODE + col[i]) * DCIN + c];
            As[r][c] = f2b(acc);
        }
    }
    __syncthreads();
    const int w = tid >> 6, l = tid & 63;
    const int ncol = l & 15, q = l >> 4, ko = q * 8;
    s8v af[4];
    #pragma unroll
    for (int kc = 0; kc < 4; ++kc)
        af[kc] = *(const s8v*)(&As[w * 16 + ncol][kc * 32 + ko]);
    float partial[4] = {0.f, 0.f, 0.f, 0.f};
    for (int nc = 0; nc < 32; ++nc) {
        int n = nc * 16 + ncol;
        const u16* brow = Wf + (size_t)n * DCIN + ko;
        f4v acc = {0.f, 0.f, 0.f, 0.f};
        #pragma unroll
        for (int kc = 0; kc < 4; ++kc)
            acc = mfma16(af[kc], *(const s8v*)(brow + kc * 32), acc);
        float bias = bfold[n];
        float l1w = l1W[n >> 1];
        #pragma unroll
        for (int rr = 0; rr < 4; ++rr) {
            float v = acc[rr] + bias;
            float o = __shfl_xor(v, 1);
            float zpre = (ncol & 1) ? o : v;
            float hpre = (ncol & 1) ? v : o;
            float hn = (1.0f - sigm(zpre)) * tanh_(hpre);
            hn = hn > 0.0f ? hn : 0.0f;
            if (!(ncol & 1)) partial[rr] += hn * l1w;
        }
    }
    #pragma unroll
    for (int rr = 0; rr < 4; ++rr) {
        float p = partial[rr];
        p += __shfl_xor(p, 1); p += __shfl_xor(p, 2);
        p += __shfl_xor(p, 4); p += __shfl_xor(p, 8);
        if (ncol == 0)
            hdot[bx * 64 + w * 16 + q * 4 + rr] = p;
    }
}

// ------ GRU: 32-block pipeline, per-wave stamps + reordered L1 (R10) -------
// syncb: [0..15]=fL0 block flags, [16..31]=fL1, [64..575]=st0[slot][w][blk],
// [576..1087]=st1. stamp value = producer step + 1.
__global__ __launch_bounds__(256)
void gru_pipe_kernel(const float* __restrict__ x,
                     const u16* __restrict__ Wpk0, const u16* __restrict__ Wpk1,
                     const float* __restrict__ bih0, const float* __restrict__ bhh0,
                     const float* __restrict__ bih1, const float* __restrict__ bhh1,
                     const float* __restrict__ l2W,
                     u16* __restrict__ h0ring, u16* __restrict__ h1ring,
                     int* syncb, float* __restrict__ gpartg) {
    __shared__ u16 wlds[16 * 3 * 512];          // 48KB max (L1); L0 uses 36KB
    __shared__ u16 tile[4][16][16];             // per-wave epilogue staging

    const int tid = threadIdx.x;
    const int w = tid >> 6;                     // wave = M-tile (16 batches)
    const int l = tid & 63;
    const int q = l >> 4, ncol = l & 15;
    const bool isL1 = blockIdx.x >= 16;
    const int rblk = blockIdx.x & 15;           // 16-channel output slice
    const int KC = isL1 ? 16 : 12;

    int* fL1 = syncb + 16;
    int* st0 = syncb + 64;
    int* st1 = syncb + 64 + 512;

    // ---- load weight slice into LDS (once) ----
    {
        const s8v* src = (const s8v*)((isL1 ? Wpk1 : Wpk0) + (size_t)rblk * KC * 3 * 512);
        s8v* dst = (s8v*)wlds;
        for (int i = tid; i < KC * 3 * 64; i += 256) dst[i] = src[i];
    }
    // ---- per-lane constants ----
    const int j = rblk * 16 + ncol;
    const float* bihp = isL1 ? bih1 : bih0;
    const float* bhhp = isL1 ? bhh1 : bhh0;
    const float br = bihp[j] + bhhp[j];
    const float bz = bihp[256 + j] + bhhp[256 + j];
    const float bi = bihp[512 + j];
    const float bhn = bhhp[512 + j];
    const float l2v = isL1 ? l2W[j] : 0.0f;
    float hreg[4] = {0.f, 0.f, 0.f, 0.f};
    const int qbase = 2 * (rblk & 1);           // publish q-half for this slice
    u16* myring = isL1 ? h1ring : h0ring;
    int* myst = isL1 ? st1 : st0;
    int* myflag = (isL1 ? fL1 : syncb) + rblk;
    const s8v* wf = (const s8v*)wlds;
    // L0's x A-fragment source: batch b = w*16+ncol, col base q*8
    const float* xrow = x + ((size_t)(w * 16 + ncol) * NNODE) * DCIN + q * 8;
    __syncthreads();

    for (int t = 0; t < NNODE; ++t) {
        const int scur = t & (RING - 1), sprev = (t - 1) & (RING - 1);
        f4v accR = {0,0,0,0}, accZ = {0,0,0,0}, accNi = {0,0,0,0}, accNh = {0,0,0,0};
        if (!isL1) {
            // phase A: x-part — no dependency, runs before any wait
            const float* xp = xrow + (size_t)t * DCIN;
            #pragma unroll
            for (int kc = 0; kc < 4; ++kc) {
                s8v a = cvt8(xp + kc * 32);
                accR  = mfma16(a, wf[(kc * 3 + 0) * 64 + l], accR);
                accZ  = mfma16(a, wf[(kc * 3 + 1) * 64 + l], accZ);
                accNi = mfma16(a, wf[(kc * 3 + 2) * 64 + l], accNi);
            }
            // phase B: wait per-wave h0(t-1) stamps (+ ring slack), then h-part
            if (t > 0) {
                wait_stamp_slack(st0 + sprev * 64 + w * 16, t, fL1, t - 7, l);
                const u64* s1 = (const u64*)(h0ring + (size_t)sprev * SLOTU16);
                s8v a1[8];
                #pragma unroll
                for (int k = 0; k < 8; ++k)
                    a1[k] = ld_ring(s1 + (size_t)(w * 8 + k) * 128 + l * 2);
                #pragma unroll
                for (int k = 0; k < 8; ++k) {
                    int kc = 4 + k;
                    accR  = mfma16(a1[k], wf[(kc * 3 + 0) * 64 + l], accR);
                    accZ  = mfma16(a1[k], wf[(kc * 3 + 1) * 64 + l], accZ);
                    accNh = mfma16(a1[k], wf[(kc * 3 + 2) * 64 + l], accNh);
                }
            }
        } else {
            // phase A: h0(t) — L0 runs ahead, wait nearly free; do it FIRST so
            // the h1 self-loop (phase B) excludes this load round trip.
            wait_stamp(st0 + scur * 64 + w * 16, t + 1, l);
            const u64* s0 = (const u64*)(h0ring + (size_t)scur * SLOTU16);
            s8v a0[8];
            #pragma unroll
            for (int k = 0; k < 8; ++k)
                a0[k] = ld_ring(s0 + (size_t)(w * 8 + k) * 128 + l * 2);
            #pragma unroll
            for (int k = 0; k < 8; ++k) {
                accR  = mfma16(a0[k], wf[(k * 3 + 0) * 64 + l], accR);
                accZ  = mfma16(a0[k], wf[(k * 3 + 1) * 64 + l], accZ);
                accNi = mfma16(a0[k], wf[(k * 3 + 2) * 64 + l], accNi);
            }
            // phase B: own h1(t-1) self-loop (binding wait, propagation
            // overlapped with phase A)
            if (t > 0) {
                wait_stamp(st1 + sprev * 64 + w * 16, t, l);
                const u64* s1 = (const u64*)(h1ring + (size_t)sprev * SLOTU16);
                s8v a1[8];
                #pragma unroll
                for (int k = 0; k < 8; ++k)
                    a1[k] = ld_ring(s1 + (size_t)(w * 8 + k) * 128 + l * 2);
                #pragma unroll
                for (int k = 0; k < 8; ++k) {
                    int kc = 8 + k;
                    accR  = mfma16(a1[k], wf[(kc * 3 + 0) * 64 + l], accR);
                    accZ  = mfma16(a1[k], wf[(kc * 3 + 1) * 64 + l], accZ);
                    accNh = mfma16(a1[k], wf[(kc * 3 + 2) * 64 + l], accNh);
                }
            }
        }
        // ---- gate epilogue (all gates in-wave; fp32 h in registers) ----
        float pd[4];
        #pragma unroll
        for (int rr = 0; rr < 4; ++rr) {
            float rv = sigm(accR[rr] + br);
            float zv = sigm(accZ[rr] + bz);
            float nv = tanh_(accNi[rr] + bi + rv * (accNh[rr] + bhn));
            float hn = nv + zv * (hreg[rr] - nv);
            hreg[rr] = hn;
            tile[w][q * 4 + rr][ncol] = f2b(hn);
            pd[rr] = hn * l2v;
        }
        // ---- publish fragment, drain, per-wave stamp (critical path) ----
        if (q == qbase || q == qbase + 1) {
            s8v v = *(const s8v*)&tile[w][ncol][8 * (q - qbase)];
            u64* dst = (u64*)(myring + (size_t)scur * SLOTU16)
                       + (size_t)(w * 8 + (rblk >> 1)) * 128 + l * 2;
            st_ring(dst, v);
        }
        asm volatile("s_waitcnt vmcnt(0)" ::: "memory");
        if (l == 0)
            __hip_atomic_store(myst + scur * 64 + w * 16 + rblk, t + 1,
                               __ATOMIC_RELAXED, __HIP_MEMORY_SCOPE_AGENT);
        // ---- off-critical-path: l2-dot partials ----
        if (isL1) {
            #pragma unroll
            for (int rr = 0; rr < 4; ++rr) {
                float v = pd[rr];
                v += __shfl_xor(v, 1); v += __shfl_xor(v, 2);
                v += __shfl_xor(v, 4); v += __shfl_xor(v, 8);
                if (ncol == 0)
                    gpartg[((size_t)t * 16 + rblk) * 64 + w * 16 + q * 4 + rr] = v;
            }
        }
        __syncthreads();   // per-step skew reset (R6: removing this regressed)
        if (tid == 0)
            __hip_atomic_store(myflag, t + 1,
                               __ATOMIC_RELAXED, __HIP_MEMORY_SCOPE_AGENT);
    }
}

// ------------------------------- final head --------------------------------
__global__ __launch_bounds__(256)
void head_kernel(const float* __restrict__ gpartg, const float* __restrict__ hdot,
                 const float* __restrict__ l1b, const float* __restrict__ l2b,
                 const float* __restrict__ l3W, const float* __restrict__ l3b,
                 float* __restrict__ out) {
    int idx = blockIdx.x * 256 + threadIdx.x;
    if (idx >= NBATCH * NNODE * 12) return;
    int r = idx / 12, oc = idx - r * 12;
    int b = r >> 9, n = r & 511;
    float g = 0.0f;
    #pragma unroll
    for (int k = 0; k < 16; ++k) g += gpartg[((size_t)n * 16 + k) * 64 + b];
    g += l2b[0];
    float hh = hdot[r] + l1b[0];
    out[idx] = g * l3W[oc] + hh * l3W[12 + oc] + l3b[oc];
}

// ---------------------- static side stream (for capture fork) --------------
static hipStream_t g_side = nullptr;
static hipEvent_t  g_evA  = nullptr;
static hipEvent_t  g_evB  = nullptr;
namespace {
struct SideInit {
    SideInit() {
        if (hipStreamCreateWithFlags(&g_side, hipStreamNonBlocking) != hipSuccess) g_side = nullptr;
        if (hipEventCreateWithFlags(&g_evA, hipEventDisableTiming) != hipSuccess) g_evA = nullptr;
        if (hipEventCreateWithFlags(&g_evB, hipEventDisableTiming) != hipSuccess) g_evB = nullptr;
    }
};
static SideInit g_side_init;
}

// ------------------------------ host launcher ------------------------------
extern "C" void kernel_launch(void* const* d_in, const int* in_sizes, int n_in,
                              void* d_out, int out_size, void* d_ws, size_t ws_size,
                              hipStream_t stream) {
    const float* x    = (const float*)d_in[0];
    const int*   ei   = (const int*)  d_in[1];
    const float* ew   = (const float*)d_in[2];
    const float* Wz   = (const float*)d_in[3];
    const float* bz   = (const float*)d_in[4];
    const float* lzW  = (const float*)d_in[5];
    const float* lzb  = (const float*)d_in[6];
    // d_in[7..10] (TGCN r-gate) unused: H0 == 0
    const float* Wh   = (const float*)d_in[11];
    const float* bh   = (const float*)d_in[12];
    const float* lhW  = (const float*)d_in[13];
    const float* lhb  = (const float*)d_in[14];
    const float* Wih0 = (const float*)d_in[15];
    const float* Whh0 = (const float*)d_in[16];
    const float* bih0 = (const float*)d_in[17];
    const float* bhh0 = (const float*)d_in[18];
    const float* Wih1 = (const float*)d_in[19];
    const float* Whh1 = (const float*)d_in[20];
    const float* bih1 = (const float*)d_in[21];
    const float* bhh1 = (const float*)d_in[22];
    const float* l1W  = (const float*)d_in[23];
    const float* l1b  = (const float*)d_in[24];
    const float* l2W  = (const float*)d_in[25];
    const float* l2b  = (const float*)d_in[26];
    const float* l3W  = (const float*)d_in[27];
    const float* l3b  = (const float*)d_in[28];

    char* ws = (char*)d_ws;
    size_t o = 0;
    auto take = [&](size_t nbytes) {
        char* p = ws + o;
        o = (o + nbytes + 255) & ~(size_t)255;
        return p;
    };
    float* deg    = (float*)take(NNODE * 4);
    float* dinv   = (float*)take(NNODE * 4);
    int*   rowptr = (int*)  take((NNODE + 1) * 4);
    int*   cursor = (int*)  take(NNODE * 4);
    int*   col    = (int*)  take((NEDGE + NNODE) * 4);
    float* val    = (float*)take((NEDGE + NNODE) * 4);
    u16*   Wf     = (u16*)  take((size_t)512 * DCIN * 2);
    float* bfold  = (float*)take(512 * 4);
    float* hdot   = (float*)take((size_t)NBATCH * NNODE * 4);
    float* gpartg = (float*)take((size_t)NNODE * 16 * 64 * 4);         // 2 MB
    u16*   Wpk0   = (u16*)  take((size_t)16 * 12 * 3 * 512 * 2);       // 590 KB
    u16*   Wpk1   = (u16*)  take((size_t)16 * 16 * 3 * 512 * 2);       // 786 KB
    u16*   h0ring = (u16*)  take((size_t)RING * SLOTU16 * 2);          // 256 KB
    u16*   h1ring = (u16*)  take((size_t)RING * SLOTU16 * 2);          // 256 KB
    int*   syncb  = (int*)  take(8192);                                // flags+stamps
    if (o > ws_size) return;   // clean-failure signature: absmax == 4.57e-2

    const bool fork = (g_side && g_evA && g_evB);
    hipStream_t sideS = fork ? g_side : stream;

    // main: init (zeroes flags + stamps + deg/counts)
    init_kernel<<<8, 256, 0, stream>>>(deg, cursor, syncb);

    if (fork) {
        hipEventRecord(g_evA, stream);
        hipStreamWaitEvent(sideS, g_evA, 0);
    }

    // side branch: graph preprocessing -> fold -> TGCN (independent of GRU)
    edge_deg_kernel<<<NEDGE / 256, 256, 0, sideS>>>(ei, ew, deg, cursor);
    scan_kernel<<<1, NNODE, 0, sideS>>>(deg, cursor, dinv, rowptr, cursor, col, val);
    fill_kernel<<<NEDGE / 256, 256, 0, sideS>>>(ei, ew, dinv, cursor, col, val);
    fold_kernel<<<512, DCIN, 0, sideS>>>(Wz, lzW, bz, lzb, Wh, lhW, bh, lhb, Wf, bfold);
    tgcn_kernel<<<512, 256, 0, sideS>>>(x, rowptr, col, val, Wf, bfold, l1W, hdot);
    if (fork) hipEventRecord(g_evB, sideS);

    // main branch: weight repacks -> GRU pipeline (x converted in-kernel)
    repack_w_kernel<<<(16 * 12 * 3 * 64 + 255) / 256, 256, 0, stream>>>(
        Wih0, Whh0, 4, 12, DCIN, DHID, Wpk0);
    repack_w_kernel<<<(16 * 16 * 3 * 64 + 255) / 256, 256, 0, stream>>>(
        Wih1, Whh1, 8, 16, DHID, DHID, Wpk1);
    gru_pipe_kernel<<<32, 256, 0, stream>>>(x, Wpk0, Wpk1, bih0, bhh0,
                                            bih1, bhh1, l2W, h0ring, h1ring,
                                            syncb, gpartg);

    // join + head
    if (fork) hipStreamWaitEvent(stream, g_evB, 0);
    head_kernel<<<(NBATCH * NNODE * 12 + 255) / 256, 256, 0, stream>>>(
        gpartg, hdot, l1b, l2b, l3W, l3b, (float*)d_out);
    (void)in_sizes; (void)n_in; (void)out_size;
}